// Round 21
// baseline (165.238 us; speedup 1.0000x reference)
//
#include <hip/hip_runtime.h>
#include <stdint.h>

#define BB 8
#define NN 2048
#define CC 64
#define KK 32
#define DK 16
#define RADIUSF 0.2f
#define EPSF 1e-8f
#define BN_EPSF 1e-5f

typedef unsigned long long u64;
typedef unsigned int u32;

// --- fp32 helpers matching the reference's arithmetic ---
__device__ __forceinline__ float refsq3(float a, float b, float c) {
  return __fadd_rn(__fadd_rn(__fmul_rn(a, a), __fmul_rn(b, b)), __fmul_rn(c, c));
}
__device__ __forceinline__ float refdot3(float ax, float ay, float az,
                                         float bx, float by, float bz) {
  return __builtin_fmaf(az, bz, __builtin_fmaf(ay, by, __fmul_rn(ax, bx)));
}
__device__ __forceinline__ float refdist(float sx, float sy, float dt) {
  float d2 = __fsub_rn(__fadd_rn(sx, sy), __fmul_rn(2.0f, dt));
  d2 = fmaxf(d2, 0.0f);
  return d2 > 0.0f ? __fsqrt_rn(d2) : 0.0f;
}
// clamped squared-distance bits (monotone proxy for the ref distance)
__device__ __forceinline__ u32 dist2b(float4 q, float4 p) {
  float dt = refdot3(q.x, q.y, q.z, p.x, p.y, p.z);
  float d2 = __fsub_rn(__fadd_rn(q.w, p.w), __fmul_rn(2.0f, dt));
  d2 = fmaxf(d2, 0.0f);
  return __float_as_uint(d2);
}
// true ref distance bits (composition identical to refdist)
__device__ __forceinline__ u32 distb(float4 q, float4 p) {
  u32 s = dist2b(q, p);
  float f = __uint_as_float(s);
  return f > 0.f ? __float_as_uint(__fsqrt_rn(f)) : 0u;
}

// cross-lane bitonic sort of one value per lane, ascending by lane (type-generic)
#define WAVE_SORT64(V)                                                        \
  {                                                                           \
    _Pragma("unroll") for (int k_ = 2; k_ <= 64; k_ <<= 1) {                  \
      _Pragma("unroll") for (int j_ = k_ >> 1; j_ >= 1; j_ >>= 1) {           \
        __typeof__(V) o_ = __shfl_xor(V, j_);                                 \
        bool keepmin_ = ((lane & k_) == 0) == ((lane & j_) == 0);             \
        __typeof__(V) mn_ = V < o_ ? V : o_;                                  \
        __typeof__(V) mx_ = V < o_ ? o_ : V;                                  \
        V = keepmin_ ? mn_ : mx_;                                             \
      }                                                                       \
    }                                                                         \
  }

// ---------------------------------------------------------------------------
// Kernel 0: pack coords + exact ref-rounded sq-norm into float4 (x,y,z,sn).
// ---------------------------------------------------------------------------
__global__ __launch_bounds__(256) void pack_kernel(const float* __restrict__ coords,
                                                   float4* __restrict__ P) {
  int t = blockIdx.x * 256 + threadIdx.x;   // 0..16383
  float x = coords[t * 3 + 0], y = coords[t * 3 + 1], z = coords[t * 3 + 2];
  P[t] = make_float4(x, y, z, refsq3(x, y, z));
}

// ---------------------------------------------------------------------------
// Kernel 1: G[b][n][c] = inv[c]*(W_f[c,:]·feats[b,:,n]) + shift[c]
// ---------------------------------------------------------------------------
__global__ __launch_bounds__(256) void gfeat_kernel(
    const float* __restrict__ feats, const float* __restrict__ conv_w,
    const float* __restrict__ gamma, const float* __restrict__ beta,
    const float* __restrict__ mean, const float* __restrict__ var,
    float* __restrict__ G) {
  __shared__ float wlds[64 * 65];
  for (int e = threadIdx.x; e < 4096; e += 256) {
    int c = e >> 6, cp = e & 63;
    wlds[c * 65 + cp] = conv_w[c * (CC + 3) + 3 + cp];
  }
  __syncthreads();
  int t = blockIdx.x * 256 + threadIdx.x;   // t = m*64 + c
  int c = t & 63;
  int m = t >> 6;                            // b*N + n
  int b = m >> 11;
  int n = m & (NN - 1);
  float inv = __fdiv_rn(gamma[c], __fsqrt_rn(__fadd_rn(var[c], BN_EPSF)));
  float shift = __fsub_rn(beta[c], __fmul_rn(mean[c], inv));
  const float* f = feats + (size_t)b * CC * NN + n;   // stride NN over c'
  float acc = 0.f;
#pragma unroll
  for (int cp = 0; cp < CC; ++cp) acc = fmaf(wlds[c * 65 + cp], f[(size_t)cp * NN], acc);
  G[t] = fmaf(inv, acc, shift);
}

// ---------------------------------------------------------------------------
// Kernel 2: exact KNN-SET, r21: STREAMING three-pass — du2[32] deleted.
// Synthesis of r12..r20: the ~51us pin = per-wave serial VALU+DS+load phases
// that cannot overlap at ~2 waves/SIMD; win condition is low instr count AND
// low VGPR together. Candidates are L1-resident (r20: FETCH 210KB w/ XCD
// swizzle), so recompute-on-demand is cheap:
//   pass 1: lane-min of d^2 bits (no array)  -> T2 = sorted A2[31] + 4ulp
//   pass 2: recompute, count survivors, scan -> write bases
//   pass 3: recompute, compact (d2,j) keys   -> one-sqrt -> u64 sort -> emit
// Recomputation is bit-identical (same inputs/ops). Sort/emit = proven r18.
// Fallback (ntot>64, cold): streaming bit-descent + two-pass emit (r17).
// ---------------------------------------------------------------------------
__global__ __launch_bounds__(256, 4) void knn_kernel(const float4* __restrict__ P,
                                                     int* __restrict__ idx_out) {
  __shared__ u64 surv[4 * 64];              // wave-private survivor strips, 2KB
  const int lane = threadIdx.x & 63;
  const int wv = threadIdx.x >> 6;
  const int bid = blockIdx.x;
  // XCD swizzle: batch from low 3 bits (XCD id under round-robin dispatch)
  const int pid = ((bid & 7) << 11) | ((bid >> 3) << 2) | wv;   // b*N + i
  const int b = pid >> 11;
  const int i = pid & (NN - 1);
  const float4* Pb = P + ((size_t)b << 11);
  float4 q = Pb[i];
  u64* sv = surv + wv * 64;
  const u64 lml = (1ull << lane) - 1ull;    // lanemask_lt

  // pass 1: lane minimum of d^2 bits (no per-candidate storage)
  u32 m0 = 0xFFFFFFFFu;
#pragma unroll
  for (int c = 0; c < 32; ++c) {
    u32 s = dist2b(q, Pb[(c << 6) | lane]);
    m0 = s < m0 ? s : m0;
  }

  // T2 = 32nd-smallest lane-minimum in d^2 bits, +4 ulp sqrt-collision slack
  // (theorem: at most 31 lane-minima < D; rank-k commutes with monotone sqrt)
  u32 Av = m0;
  WAVE_SORT64(Av);
  const u32 T2 = __shfl(Av, 31) + 4u;

  // pass 2: survivor count (recompute) + exclusive scan -> write base
  u32 cls = 0;
#pragma unroll
  for (int c = 0; c < 32; ++c) cls += (dist2b(q, Pb[(c << 6) | lane]) <= T2) ? 1u : 0u;
  u32 v2 = cls;
#pragma unroll
  for (int sft = 1; sft < 64; sft <<= 1) {
    u32 o = __shfl_up(v2, sft, 64);
    if (lane >= sft) v2 += o;
  }
  const u32 ntot = __shfl(v2, 63);
  int* op = idx_out + (size_t)pid * KK;

  if (ntot <= 64) {
    // pass 3: recompute + compact survivor (d2,j) keys
    u32 pos = v2 - cls;
#pragma unroll
    for (int c = 0; c < 32; ++c) {
      int j = (c << 6) | lane;
      u32 s = dist2b(q, Pb[j]);
      if (s <= T2) {
        sv[pos] = ((u64)s << 32) | (u64)(u32)j;
        ++pos;
      }
    }
    // convert to TRUE d bits with ONE wave-wide sqrt, then exact (d,j) sort
    u64 x = ~0ull;
    if (lane < (int)ntot) {
      u64 raw = sv[lane];
      float d2f = __uint_as_float((u32)(raw >> 32));
      u32 dbits = d2f > 0.f ? __float_as_uint(__fsqrt_rn(d2f)) : 0u;
      x = ((u64)dbits << 32) | (raw & 0xFFFFFFFFull);
    }
    WAVE_SORT64(x);
    if (lane < KK) op[lane] = (int)((u32)x & 0x7FFu);
  } else {
    // cold fallback: streaming bit-descent for D (true d bits), two-pass emit
    u32 ans = 0;
#pragma unroll 1
    for (int bbit = 30; bbit >= 0; --bbit) {
      u32 t3 = ans | (1u << bbit);
      u32 c2 = 0;
#pragma unroll
      for (int c = 0; c < 32; ++c)
        c2 += (distb(q, Pb[(c << 6) | lane]) < t3) ? 1u : 0u;
#pragma unroll
      for (int sft = 1; sft < 64; sft <<= 1) c2 += __shfl_xor(c2, sft);
      if (c2 < KK) ans = t3;
    }
    const u32 D = ans;
    u32 cntL = 0;
#pragma unroll
    for (int c = 0; c < 32; ++c)
      cntL += (distb(q, Pb[(c << 6) | lane]) < D) ? 1u : 0u;
    u32 vL = cntL;
#pragma unroll
    for (int sft = 1; sft < 64; sft <<= 1) {
      u32 o = __shfl_up(vL, sft, 64);
      if (lane >= sft) vL += o;
    }
    const u32 r = KK - __shfl(vL, 63);
    u32 pos = vL - cntL;
#pragma unroll
    for (int c = 0; c < 32; ++c) {
      int j = (c << 6) | lane;
      if (distb(q, Pb[j]) < D) { op[pos] = j; ++pos; }
    }
    u32 emit = r;
    u32 wpos = KK - r;
#pragma unroll
    for (int c = 0; c < 32; ++c) {
      if (emit != 0) {
        int j = (c << 6) | lane;
        bool eq = distb(q, Pb[j]) == D;
        u64 mk = __ballot(eq);
        u32 pc = (u32)__popcll(mk);
        u32 rk = (u32)__popcll(mk & lml);
        if (eq && rk < emit) op[wpos + rk] = j;
        u32 take = pc < emit ? pc : emit;
        wpos += take;
        emit -= take;
      }
    }
  }
}

// ---------------------------------------------------------------------------
// Kernel 3: fused density + aggregation, two points per wave; agg broadcast
// via LDS (r16, proven).
// ---------------------------------------------------------------------------
__global__ __launch_bounds__(256) void dagg_kernel(
    const float4* __restrict__ P, const float* __restrict__ conv_w,
    const float* __restrict__ gamma, const float* __restrict__ var,
    const float* __restrict__ G, const int* __restrict__ idxb,
    float* __restrict__ out) {
  __shared__ float4 ldsRW[4][64];           // (rx,ry,rz,wk) per lane
  __shared__ int ldsJ[4][64];               // pre-scaled j*64 row offsets
  const int lane = threadIdx.x & 63;
  const int wv = threadIdx.x >> 6;
  const int half = lane >> 5;
  const int k = lane & 31;
  const int pid_pair = blockIdx.x * 8 + wv * 2;   // even; never crosses batch
  const int pid = pid_pair + half;                 // this half's point
  const int b = pid >> 11;
  const float4* Pb = P + ((size_t)b << 11);

  const int i = pid & (NN - 1);
  float4 q = Pb[i];                       // broadcast within each half
  int jk = idxb[(size_t)pid * KK + k];    // neighbor index (lane half*32+k)
  float4 nb = Pb[jk];                     // neighbor coords + refsq3 norm

  float rx = __fdiv_rn(__fsub_rn(nb.x, q.x), RADIUSF);
  float ry = __fdiv_rn(__fsub_rn(nb.y, q.y), RADIUSF);
  float rz = __fdiv_rn(__fsub_rn(nb.z, q.z), RADIUSF);

  // --- density phase (per half): 16th smallest of 32 neighbor-distances ---
  u32 d2b[32];
#pragma unroll
  for (int t = 0; t < 32; ++t) {
    float ox = __shfl(nb.x, t, 32);
    float oy = __shfl(nb.y, t, 32);
    float oz = __shfl(nb.z, t, 32);
    float so = __shfl(nb.w, t, 32);
    float dt = refdot3(nb.x, nb.y, nb.z, ox, oy, oz);
    float d2 = __fsub_rn(__fadd_rn(nb.w, so), __fmul_rn(2.0f, dt));
    d2 = fmaxf(d2, 0.0f);
    d2b[t] = (t == k) ? 0x7F800000u : __float_as_uint(d2);  // eye = +inf
  }
#pragma unroll
  for (int p = 1; p < 32; p <<= 1) {
#pragma unroll
    for (int kk = p; kk >= 1; kk >>= 1) {
#pragma unroll
      for (int jj = (kk & (p - 1)); jj + kk < 32; jj += 2 * kk) {
#pragma unroll
        for (int t = 0; t < kk; ++t) {
          if ((t + jj) / (2 * p) == (t + jj + kk) / (2 * p)) {
            u32 a = d2b[t + jj], b2 = d2b[t + jj + kk];
            d2b[t + jj] = a < b2 ? a : b2;
            d2b[t + jj + kk] = a < b2 ? b2 : a;
          }
        }
      }
    }
  }
  float kd2 = __uint_as_float(d2b[DK - 1]);
  float kth = kd2 > 0.f ? __fsqrt_rn(kd2) : 0.f;
  float r1 = fmaxf(kth, EPSF);
  float raw = __fmul_rn(__fmul_rn(r1, r1), r1);
  float s = raw;
#pragma unroll
  for (int t = 1; t < 32; t <<= 1) s += __shfl_xor(s, t, 32);
  float wk = raw / fmaxf(s, EPSF);        // w_k in lane half*32+k

  ldsRW[wv][lane] = make_float4(rx, ry, rz, wk);
  ldsJ[wv][lane] = jk * 64;

  // --- agg phase: lane = channel; two points sequentially ---
  float inv = __fdiv_rn(gamma[lane], __fsqrt_rn(__fadd_rn(var[lane], BN_EPSF)));
  float w0 = conv_w[lane * (CC + 3) + 0] * inv;
  float w1 = conv_w[lane * (CC + 3) + 1] * inv;
  float w2 = conv_w[lane * (CC + 3) + 2] * inv;
  const float* Gb = G + ((size_t)b * NN) * 64 + lane;

#pragma unroll
  for (int h2 = 0; h2 < 2; ++h2) {
    const int pid2 = pid_pair + h2;
    const int i2 = pid2 & (NN - 1);
    float acc = 0.f;
#pragma unroll
    for (int kk2 = 0; kk2 < KK; ++kk2) {
      float4 rw = ldsRW[wv][h2 * 32 + kk2];   // broadcast read
      int joff = ldsJ[wv][h2 * 32 + kk2];
      float g = Gb[joff];
      float y = fmaf(w2, rw.z, fmaf(w1, rw.y, fmaf(w0, rw.x, g)));
      y = fmaxf(y, 0.f);
      acc = fmaf(rw.w, y, acc);
    }
    out[((size_t)(b * 64 + lane)) * NN + i2] = acc;
  }
}

// ---------------------------------------------------------------------------
extern "C" void kernel_launch(void* const* d_in, const int* in_sizes, int n_in,
                              void* d_out, int out_size, void* d_ws, size_t ws_size,
                              hipStream_t stream) {
  const float* coords = (const float*)d_in[0];
  const float* feats  = (const float*)d_in[1];
  const float* conv_w = (const float*)d_in[2];
  const float* gamma  = (const float*)d_in[3];
  const float* beta   = (const float*)d_in[4];
  const float* mean   = (const float*)d_in[5];
  const float* var    = (const float*)d_in[6];
  float* out = (float*)d_out;

  int*   idxb = (int*)d_ws;                                          // 2 MB
  float4* P   = (float4*)((char*)d_ws + (size_t)2 * 1024 * 1024);    // 256 KB
  float* G    = (float*)((char*)d_ws + (size_t)4 * 1024 * 1024);     // 4 MB

  const int NPTS = BB * NN;   // 16384

  pack_kernel<<<NPTS / 256, 256, 0, stream>>>(coords, P);
  knn_kernel<<<NPTS / 4, 256, 0, stream>>>(P, idxb);
  gfeat_kernel<<<(NPTS * CC) / 256, 256, 0, stream>>>(feats, conv_w, gamma, beta,
                                                      mean, var, G);
  dagg_kernel<<<NPTS / 8, 256, 0, stream>>>(P, conv_w, gamma, var, G, idxb, out);
}

// Round 22
// 80.382 us; speedup vs baseline: 2.0557x; 2.0557x over previous
//
#include <hip/hip_runtime.h>
#include <stdint.h>

#define BB 8
#define NN 2048
#define CC 64
#define KK 32
#define DK 16
#define RADIUSF 0.2f
#define EPSF 1e-8f
#define BN_EPSF 1e-5f

typedef unsigned long long u64;
typedef unsigned int u32;

// --- fp32 helpers matching the reference's arithmetic ---
__device__ __forceinline__ float refsq3(float a, float b, float c) {
  return __fadd_rn(__fadd_rn(__fmul_rn(a, a), __fmul_rn(b, b)), __fmul_rn(c, c));
}
__device__ __forceinline__ float refdot3(float ax, float ay, float az,
                                         float bx, float by, float bz) {
  return __builtin_fmaf(az, bz, __builtin_fmaf(ay, by, __fmul_rn(ax, bx)));
}
__device__ __forceinline__ float refdist(float sx, float sy, float dt) {
  float d2 = __fsub_rn(__fadd_rn(sx, sy), __fmul_rn(2.0f, dt));
  d2 = fmaxf(d2, 0.0f);
  return d2 > 0.0f ? __fsqrt_rn(d2) : 0.0f;
}

// cross-lane bitonic sort of one value per lane, ascending by lane (type-generic)
#define WAVE_SORT64(V)                                                        \
  {                                                                           \
    _Pragma("unroll") for (int k_ = 2; k_ <= 64; k_ <<= 1) {                  \
      _Pragma("unroll") for (int j_ = k_ >> 1; j_ >= 1; j_ >>= 1) {           \
        __typeof__(V) o_ = __shfl_xor(V, j_);                                 \
        bool keepmin_ = ((lane & k_) == 0) == ((lane & j_) == 0);             \
        __typeof__(V) mn_ = V < o_ ? V : o_;                                  \
        __typeof__(V) mx_ = V < o_ ? o_ : V;                                  \
        V = keepmin_ ? mn_ : mx_;                                             \
      }                                                                       \
    }                                                                         \
  }

// ---------------------------------------------------------------------------
// Kernel 0: pack coords + exact ref-rounded sq-norm into float4 (x,y,z,sn).
// ---------------------------------------------------------------------------
__global__ __launch_bounds__(256) void pack_kernel(const float* __restrict__ coords,
                                                   float4* __restrict__ P) {
  int t = blockIdx.x * 256 + threadIdx.x;   // 0..16383
  float x = coords[t * 3 + 0], y = coords[t * 3 + 1], z = coords[t * 3 + 2];
  P[t] = make_float4(x, y, z, refsq3(x, y, z));
}

// ---------------------------------------------------------------------------
// Kernel 1: G[b][n][c] = inv[c]*(W_f[c,:]·feats[b,:,n]) + shift[c]
// ---------------------------------------------------------------------------
__global__ __launch_bounds__(256) void gfeat_kernel(
    const float* __restrict__ feats, const float* __restrict__ conv_w,
    const float* __restrict__ gamma, const float* __restrict__ beta,
    const float* __restrict__ mean, const float* __restrict__ var,
    float* __restrict__ G) {
  __shared__ float wlds[64 * 65];
  for (int e = threadIdx.x; e < 4096; e += 256) {
    int c = e >> 6, cp = e & 63;
    wlds[c * 65 + cp] = conv_w[c * (CC + 3) + 3 + cp];
  }
  __syncthreads();
  int t = blockIdx.x * 256 + threadIdx.x;   // t = m*64 + c
  int c = t & 63;
  int m = t >> 6;                            // b*N + n
  int b = m >> 11;
  int n = m & (NN - 1);
  float inv = __fdiv_rn(gamma[c], __fsqrt_rn(__fadd_rn(var[c], BN_EPSF)));
  float shift = __fsub_rn(beta[c], __fmul_rn(mean[c], inv));
  const float* f = feats + (size_t)b * CC * NN + n;   // stride NN over c'
  float acc = 0.f;
#pragma unroll
  for (int cp = 0; cp < CC; ++cp) acc = fmaf(wlds[c * 65 + cp], f[(size_t)cp * NN], acc);
  G[t] = fmaf(inv, acc, shift);
}

// ---------------------------------------------------------------------------
// Kernel 2: exact KNN-SET — proven r18 body (80.6us total config).
// Hot loop in d^2-bit space (no sqrt). T2 = sorted-lane-minima[31] + 4ulp
// (theorem: at most 31 lane-minima < D; +4ulp covers sqrt rounding
// collisions). Survivors compacted as (d2,j) keys; ONE wave-wide sqrt
// converts to true d bits; u64 (d,j) sort-64 -> first 32 lanes = answer
// (exact value-then-index reference tie-break). Fallback (ntot>64, cold):
// d-bit conversion + bit-descent + two-pass emit.
// ---------------------------------------------------------------------------
__global__ __launch_bounds__(256) void knn_kernel(const float4* __restrict__ P,
                                                  int* __restrict__ idx_out) {
  __shared__ u64 surv[4 * 64];              // wave-private survivor strips, 2KB
  const int lane = threadIdx.x & 63;
  const int wv = threadIdx.x >> 6;
  const int pid = blockIdx.x * 4 + wv;      // b*N + i
  const int b = pid >> 11;
  const int i = pid & (NN - 1);
  const float4* Pb = P + ((size_t)b << 11);
  float4 q = Pb[i];
  u64* sv = surv + wv * 64;
  const u64 lml = (1ull << lane) - 1ull;    // lanemask_lt

  u32 du2[32];                              // clamped d^2 bits (no sqrt)
  u32 m0 = 0xFFFFFFFFu;                     // lane minimum (d^2 bits)
#pragma unroll
  for (int c = 0; c < 32; ++c) {
    int j = (c << 6) | lane;
    float4 p = Pb[j];
    float dt = refdot3(q.x, q.y, q.z, p.x, p.y, p.z);
    float d2 = __fsub_rn(__fadd_rn(q.w, p.w), __fmul_rn(2.0f, dt));
    d2 = fmaxf(d2, 0.0f);
    u32 s = __float_as_uint(d2);
    du2[c] = s;
    m0 = s < m0 ? s : m0;
  }

  // T2 = 32nd-smallest lane-minimum in d^2 bits, +4 ulp sqrt-collision slack
  u32 Av = m0;
  WAVE_SORT64(Av);
  const u32 T2 = __shfl(Av, 31) + 4u;

  // survivor count + exclusive scan -> per-lane write base
  u32 cls = 0;
#pragma unroll
  for (int c = 0; c < 32; ++c) cls += (du2[c] <= T2) ? 1u : 0u;
  u32 v2 = cls;
#pragma unroll
  for (int sft = 1; sft < 64; sft <<= 1) {
    u32 o = __shfl_up(v2, sft, 64);
    if (lane >= sft) v2 += o;
  }
  const u32 ntot = __shfl(v2, 63);
  int* op = idx_out + (size_t)pid * KK;

  if (ntot <= 64) {
    // compact survivor (d2,j) keys (per-lane sequential writes)
    u32 pos = v2 - cls;
#pragma unroll
    for (int c = 0; c < 32; ++c) {
      if (du2[c] <= T2) {
        sv[pos] = ((u64)du2[c] << 32) | (u64)(u32)((c << 6) | lane);
        ++pos;
      }
    }
    // convert to TRUE d bits with ONE wave-wide sqrt, then exact (d,j) sort
    u64 x = ~0ull;
    if (lane < (int)ntot) {
      u64 raw = sv[lane];
      float d2f = __uint_as_float((u32)(raw >> 32));
      u32 dbits = d2f > 0.f ? __float_as_uint(__fsqrt_rn(d2f)) : 0u;
      x = ((u64)dbits << 32) | (raw & 0xFFFFFFFFull);
    }
    WAVE_SORT64(x);
    if (lane < KK) op[lane] = (int)((u32)x & 0x7FFu);
  } else {
    // cold fallback: convert to d bits, then bit-descent + two-pass emit
#pragma unroll
    for (int c = 0; c < 32; ++c) {
      float d2f = __uint_as_float(du2[c]);
      du2[c] = d2f > 0.f ? __float_as_uint(__fsqrt_rn(d2f)) : 0u;
    }
    u32 ans = 0;
#pragma unroll 1
    for (int bbit = 30; bbit >= 0; --bbit) {
      u32 t2 = ans | (1u << bbit);
      u32 c2 = 0;
#pragma unroll
      for (int c = 0; c < 32; ++c) c2 += (du2[c] < t2) ? 1u : 0u;
#pragma unroll
      for (int sft = 1; sft < 64; sft <<= 1) c2 += __shfl_xor(c2, sft);
      if (c2 < KK) ans = t2;
    }
    const u32 D = ans;
    u32 cntL = 0;
#pragma unroll
    for (int c = 0; c < 32; ++c) cntL += (du2[c] < D) ? 1u : 0u;
    u32 vL = cntL;
#pragma unroll
    for (int sft = 1; sft < 64; sft <<= 1) {
      u32 o = __shfl_up(vL, sft, 64);
      if (lane >= sft) vL += o;
    }
    const u32 r = KK - __shfl(vL, 63);
    u32 pos = vL - cntL;
#pragma unroll
    for (int c = 0; c < 32; ++c) {
      if (du2[c] < D) { op[pos] = (c << 6) | lane; ++pos; }
    }
    u32 emit = r;
    u32 wpos = KK - r;
#pragma unroll
    for (int c = 0; c < 32; ++c) {
      if (emit != 0) {
        u64 mk = __ballot(du2[c] == D);
        u32 pc = (u32)__popcll(mk);
        u32 rk = (u32)__popcll(mk & lml);
        if ((du2[c] == D) && rk < emit) op[wpos + rk] = (c << 6) | lane;
        u32 take = pc < emit ? pc : emit;
        wpos += take;
        emit -= take;
      }
    }
  }
}

// ---------------------------------------------------------------------------
// Kernel 3: fused density + aggregation, two points per wave; agg broadcast
// via LDS (r16, proven).
// ---------------------------------------------------------------------------
__global__ __launch_bounds__(256) void dagg_kernel(
    const float4* __restrict__ P, const float* __restrict__ conv_w,
    const float* __restrict__ gamma, const float* __restrict__ var,
    const float* __restrict__ G, const int* __restrict__ idxb,
    float* __restrict__ out) {
  __shared__ float4 ldsRW[4][64];           // (rx,ry,rz,wk) per lane
  __shared__ int ldsJ[4][64];               // pre-scaled j*64 row offsets
  const int lane = threadIdx.x & 63;
  const int wv = threadIdx.x >> 6;
  const int half = lane >> 5;
  const int k = lane & 31;
  const int pid_pair = blockIdx.x * 8 + wv * 2;   // even; never crosses batch
  const int pid = pid_pair + half;                 // this half's point
  const int b = pid >> 11;
  const float4* Pb = P + ((size_t)b << 11);

  const int i = pid & (NN - 1);
  float4 q = Pb[i];                       // broadcast within each half
  int jk = idxb[(size_t)pid * KK + k];    // neighbor index (lane half*32+k)
  float4 nb = Pb[jk];                     // neighbor coords + refsq3 norm

  float rx = __fdiv_rn(__fsub_rn(nb.x, q.x), RADIUSF);
  float ry = __fdiv_rn(__fsub_rn(nb.y, q.y), RADIUSF);
  float rz = __fdiv_rn(__fsub_rn(nb.z, q.z), RADIUSF);

  // --- density phase (per half): 16th smallest of 32 neighbor-distances ---
  u32 d2b[32];
#pragma unroll
  for (int t = 0; t < 32; ++t) {
    float ox = __shfl(nb.x, t, 32);
    float oy = __shfl(nb.y, t, 32);
    float oz = __shfl(nb.z, t, 32);
    float so = __shfl(nb.w, t, 32);
    float dt = refdot3(nb.x, nb.y, nb.z, ox, oy, oz);
    float d2 = __fsub_rn(__fadd_rn(nb.w, so), __fmul_rn(2.0f, dt));
    d2 = fmaxf(d2, 0.0f);
    d2b[t] = (t == k) ? 0x7F800000u : __float_as_uint(d2);  // eye = +inf
  }
#pragma unroll
  for (int p = 1; p < 32; p <<= 1) {
#pragma unroll
    for (int kk = p; kk >= 1; kk >>= 1) {
#pragma unroll
      for (int jj = (kk & (p - 1)); jj + kk < 32; jj += 2 * kk) {
#pragma unroll
        for (int t = 0; t < kk; ++t) {
          if ((t + jj) / (2 * p) == (t + jj + kk) / (2 * p)) {
            u32 a = d2b[t + jj], b2 = d2b[t + jj + kk];
            d2b[t + jj] = a < b2 ? a : b2;
            d2b[t + jj + kk] = a < b2 ? b2 : a;
          }
        }
      }
    }
  }
  float kd2 = __uint_as_float(d2b[DK - 1]);
  float kth = kd2 > 0.f ? __fsqrt_rn(kd2) : 0.f;
  float r1 = fmaxf(kth, EPSF);
  float raw = __fmul_rn(__fmul_rn(r1, r1), r1);
  float s = raw;
#pragma unroll
  for (int t = 1; t < 32; t <<= 1) s += __shfl_xor(s, t, 32);
  float wk = raw / fmaxf(s, EPSF);        // w_k in lane half*32+k

  ldsRW[wv][lane] = make_float4(rx, ry, rz, wk);
  ldsJ[wv][lane] = jk * 64;

  // --- agg phase: lane = channel; two points sequentially ---
  float inv = __fdiv_rn(gamma[lane], __fsqrt_rn(__fadd_rn(var[lane], BN_EPSF)));
  float w0 = conv_w[lane * (CC + 3) + 0] * inv;
  float w1 = conv_w[lane * (CC + 3) + 1] * inv;
  float w2 = conv_w[lane * (CC + 3) + 2] * inv;
  const float* Gb = G + ((size_t)b * NN) * 64 + lane;

#pragma unroll
  for (int h2 = 0; h2 < 2; ++h2) {
    const int pid2 = pid_pair + h2;
    const int i2 = pid2 & (NN - 1);
    float acc = 0.f;
#pragma unroll
    for (int kk2 = 0; kk2 < KK; ++kk2) {
      float4 rw = ldsRW[wv][h2 * 32 + kk2];   // broadcast read
      int joff = ldsJ[wv][h2 * 32 + kk2];
      float g = Gb[joff];
      float y = fmaf(w2, rw.z, fmaf(w1, rw.y, fmaf(w0, rw.x, g)));
      y = fmaxf(y, 0.f);
      acc = fmaf(rw.w, y, acc);
    }
    out[((size_t)(b * 64 + lane)) * NN + i2] = acc;
  }
}

// ---------------------------------------------------------------------------
extern "C" void kernel_launch(void* const* d_in, const int* in_sizes, int n_in,
                              void* d_out, int out_size, void* d_ws, size_t ws_size,
                              hipStream_t stream) {
  const float* coords = (const float*)d_in[0];
  const float* feats  = (const float*)d_in[1];
  const float* conv_w = (const float*)d_in[2];
  const float* gamma  = (const float*)d_in[3];
  const float* beta   = (const float*)d_in[4];
  const float* mean   = (const float*)d_in[5];
  const float* var    = (const float*)d_in[6];
  float* out = (float*)d_out;

  int*   idxb = (int*)d_ws;                                          // 2 MB
  float4* P   = (float4*)((char*)d_ws + (size_t)2 * 1024 * 1024);    // 256 KB
  float* G    = (float*)((char*)d_ws + (size_t)4 * 1024 * 1024);     // 4 MB

  const int NPTS = BB * NN;   // 16384

  pack_kernel<<<NPTS / 256, 256, 0, stream>>>(coords, P);
  knn_kernel<<<NPTS / 4, 256, 0, stream>>>(P, idxb);
  gfeat_kernel<<<(NPTS * CC) / 256, 256, 0, stream>>>(feats, conv_w, gamma, beta,
                                                      mean, var, G);
  dagg_kernel<<<NPTS / 8, 256, 0, stream>>>(P, conv_w, gamma, var, G, idxb, out);
}